// Round 10
// baseline (200.319 us; speedup 1.0000x reference)
//
#include <hip/hip_runtime.h>
#include <stdint.h>

#define DIM 768
#define HEADS 12
#define HD 64
#define BATCH 4
#define SEQ 1024
#define NTOK (BATCH*SEQ)   // 4096
#define QKVW (3*DIM)       // 2304
#define QKW (2*DIM)        // 1536
#define EPS 1e-5f

typedef __attribute__((ext_vector_type(8))) short short8;   // 8 bf16 (4 VGPRs)
typedef __attribute__((ext_vector_type(4))) float f32x4;    // MFMA C/D

// ---- fp32 <-> bf16 ----
__device__ __forceinline__ unsigned short f2bf(float f) {
    union { float f; unsigned u; } v; v.f = f;
    unsigned r = v.u + 0x7fffu + ((v.u >> 16) & 1u);   // RNE
    return (unsigned short)(r >> 16);
}
__device__ __forceinline__ float b2f(unsigned short s) {
    union { unsigned u; float f; } v; v.u = (unsigned)s << 16; return v.f;
}

// ---- async global->LDS, 16B per lane ----
__device__ __forceinline__ void gld_lds16(const void* g, void* l) {
    auto gp = reinterpret_cast<const __attribute__((address_space(1))) unsigned int*>(
        (uintptr_t)g);
    auto lp = reinterpret_cast<__attribute__((address_space(3))) unsigned int*>(
        (unsigned int)(uintptr_t)l);
    __builtin_amdgcn_global_load_lds(gp, lp, 16, 0, 0);
}

// ==================== combined conversions (1 launch) ====================
#define CVT_X_BLOCKS (NTOK*DIM/4096)            // 768 (4 float4 per thread)
#define CVT_WQ_TILES ((QKVW/32)*(DIM/32))       // 1728
#define CVT_WP_TILES ((DIM/32)*(DIM/32))        // 576
__global__ __launch_bounds__(256) void cvt_all_kernel(
    const float* __restrict__ x,
    const float* __restrict__ Wq0, const float* __restrict__ Wq1,
    const float* __restrict__ Wp0, const float* __restrict__ Wp1,
    unsigned short* __restrict__ xb,
    unsigned short* __restrict__ WqT0, unsigned short* __restrict__ WqT1,
    unsigned short* __restrict__ WpT0, unsigned short* __restrict__ WpT1)
{
    const int bid = blockIdx.x, tid = threadIdx.x;
    if (bid < CVT_X_BLOCKS) {
        const int base = bid * 1024 + tid;
#pragma unroll
        for (int u = 0; u < 4; ++u) {
            const float4 v = ((const float4*)x)[base + u * 256];
            ushort4 o4;
            o4.x = f2bf(v.x); o4.y = f2bf(v.y); o4.z = f2bf(v.z); o4.w = f2bf(v.w);
            ((ushort4*)xb)[base + u * 256] = o4;
        }
        return;
    }
    __shared__ float t[32][33];
    const float* W; unsigned short* WT; int N, K, tile;
    int w = bid - CVT_X_BLOCKS;
    if (w < 2 * CVT_WQ_TILES) {
        const int z = w / CVT_WQ_TILES; tile = w % CVT_WQ_TILES;
        W = z ? Wq1 : Wq0; WT = z ? WqT1 : WqT0; N = QKVW; K = DIM;
    } else {
        w -= 2 * CVT_WQ_TILES;
        const int z = w / CVT_WP_TILES; tile = w % CVT_WP_TILES;
        W = z ? Wp1 : Wp0; WT = z ? WpT1 : WpT0; N = DIM; K = DIM;
    }
    const int ntiles = N / 32;
    const int n0 = (tile % ntiles) * 32, k0 = (tile / ntiles) * 32;
    const int c = tid & 31, rr = tid >> 5;
#pragma unroll
    for (int i = 0; i < 4; ++i)
        t[rr + 8 * i][c] = W[(size_t)(k0 + rr + 8 * i) * N + n0 + c];
    __syncthreads();
#pragma unroll
    for (int i = 0; i < 4; ++i)
        WT[(size_t)(n0 + rr + 8 * i) * K + k0 + c] = f2bf(t[c][rr + 8 * i]);
}

// ==================== fused QKV GEMM — R20: 256x128 x BK32, 2 blk/CU =======
// Last untried tile-geometry corner: 256x128 fixes BOTH prior failure modes
// (256^2: 1 blk/CU + tail; 128^2: 24 staged B/output-elem). Here: 18 B/elem
// (-27% staging traffic), 12 ds_read per 32 MFMA/wave (was 16), LDS 48KB ->
// 2 blk/CU, grid 576 -> 1.125 rounds. Reuses only verified pieces: R15/R16
// BK-32 4-chunk swizzle, R14 sync order, R12 two-half epilogue, R16 2D XCD
// supertile. K-ascending accumulation (absmax unchanged).
__global__ __launch_bounds__(256, 2) void gemm_qkv_kernel(
    const unsigned short* __restrict__ A,     // xb [4096][768]
    const unsigned short* __restrict__ BT0, const unsigned short* __restrict__ BT1,
    const float* __restrict__ bias0, const float* __restrict__ bias1,
    unsigned short* __restrict__ QK0, unsigned short* __restrict__ QK1,
    unsigned short* __restrict__ VT0, unsigned short* __restrict__ VT1)
{
    const int gid = blockIdx.x;
    // 2D XCD supertile: XCD g=(r,c) in 2x4 owns by[8r,8r+8) x bxz[9c,9c+9)
    const int g = gid & 7, l = gid >> 3;           // l in [0,72)
    const int by  = (g >> 2) * 8 + (l & 7);        // 0..15 (M tiles of 256)
    const int bxz = (g & 3) * 9 + (l >> 3);        // 0..35
    const int z = (bxz >= 18) ? 1 : 0;
    const int bx = z ? bxz - 18 : bxz;             // branch-local N tile 0..17
    const unsigned short* __restrict__ BT = z ? BT1 : BT0;
    const float* __restrict__ bias = z ? bias1 : bias0;
    unsigned short* __restrict__ QK = z ? QK1 : QK0;
    unsigned short* __restrict__ VT = z ? VT1 : VT0;
    const int m0 = by * 256;
    const int nb0 = bx * 128;

    // LDS 24576 shorts = 48 KiB: A dbuf 2x8192, B dbuf 2x4096 (@16384).
    // Epilogue reuses [0,17408) as C tile [128][136] (two half-passes).
    __shared__ __align__(16) unsigned short lds[24576];

    const int tid = threadIdx.x, lane = tid & 63, wv = tid >> 6;
    const int fm = lane & 15, fg = lane >> 4;
    const int wr = wv >> 1, wc = wv & 1;            // wave grid 2(M) x 2(N)

    // staging (R15/R16-verified BK32 map): slot s -> row s>>2, global chunk
    // (s&3)^((s>>3)&3); per call 256 threads cover 64 rows x 32k
    const int s4 = lane >> 2;                       // 0..15
    const int sc = ((lane & 3) ^ ((lane >> 3) & 3)) * 8;
    const unsigned short* pA = A  + (size_t)(m0  + wv * 16 + s4) * DIM + sc;
    const unsigned short* pB = BT + (size_t)(nb0 + wv * 16 + s4) * DIM + sc;
    unsigned short* dA = lds + wv * 512;            // wave-uniform dest bases
    unsigned short* dB = lds + 16384 + wv * 512;

    // ds_read (R15-verified): element (row, k-chunk fg) at chunk fg^((row>>1)&3)
    const int cR = (fg ^ ((fm >> 1) & 3)) * 8;
    const int aB = (wr * 128 + fm) * 32;            // wave M-base (128 rows)
    const int bB = (wc * 64 + fm) * 32;             // wave N-base (64 cols)

    f32x4 acc[8][4];
#pragma unroll
    for (int i = 0; i < 8; ++i)
#pragma unroll
        for (int j = 0; j < 4; ++j) acc[i][j] = f32x4{0.f, 0.f, 0.f, 0.f};

    short8 a[8], b[4];

#define STAGE(kt, buf) do {                                        \
        const int ko_ = (kt) * 32;                                 \
        gld_lds16(pA + ko_,             dA + (buf) * 8192);        \
        gld_lds16(pA + ko_ +  64 * DIM, dA + (buf) * 8192 + 2048); \
        gld_lds16(pA + ko_ + 128 * DIM, dA + (buf) * 8192 + 4096); \
        gld_lds16(pA + ko_ + 192 * DIM, dA + (buf) * 8192 + 6144); \
        gld_lds16(pB + ko_,             dB + (buf) * 4096);        \
        gld_lds16(pB + ko_ +  64 * DIM, dB + (buf) * 4096 + 2048); \
    } while (0)

    STAGE(0, 0);

    for (int t = 0; t < 24; ++t) {
        const int ab = (t & 1) * 8192;              // A buffer (read)
        const int bb = 16384 + (t & 1) * 4096;      // B buffer (read)

        // own stage(t) landed; barrier -> all waves' landed AND all readers of
        // the other buffer (tile t-1) are done -> safe to overwrite (R14 order)
        asm volatile("s_waitcnt vmcnt(0)" ::: "memory");
        __builtin_amdgcn_s_barrier();
        if (t < 23) STAGE(t + 1, (t + 1) & 1);

        // ---- cluster 1: A mi=0..7 (8 reads) + B nj=0,1 (2 reads); 16 mfma
#pragma unroll
        for (int mi = 0; mi < 8; ++mi)
            a[mi] = *(const short8*)&lds[ab + aB + mi * 512 + cR];
#pragma unroll
        for (int nj = 0; nj < 2; ++nj)
            b[nj] = *(const short8*)&lds[bb + bB + nj * 512 + cR];
        asm volatile("s_waitcnt lgkmcnt(0)" ::: "memory");
        __builtin_amdgcn_sched_barrier(0);
        __builtin_amdgcn_s_setprio(1);
#pragma unroll
        for (int mi = 0; mi < 8; ++mi)
#pragma unroll
            for (int nj = 0; nj < 2; ++nj)
                acc[mi][nj] = __builtin_amdgcn_mfma_f32_16x16x32_bf16(
                    a[mi], b[nj], acc[mi][nj], 0, 0, 0);
        __builtin_amdgcn_s_setprio(0);

        // ---- cluster 2: B nj=2,3 (2 reads); 16 mfma
#pragma unroll
        for (int nj = 2; nj < 4; ++nj)
            b[nj] = *(const short8*)&lds[bb + bB + nj * 512 + cR];
        asm volatile("s_waitcnt lgkmcnt(0)" ::: "memory");
        __builtin_amdgcn_sched_barrier(0);
        __builtin_amdgcn_s_setprio(1);
#pragma unroll
        for (int mi = 0; mi < 8; ++mi)
#pragma unroll
            for (int nj = 2; nj < 4; ++nj)
                acc[mi][nj] = __builtin_amdgcn_mfma_f32_16x16x32_bf16(
                    a[mi], b[nj], acc[mi][nj], 0, 0, 0);
        __builtin_amdgcn_s_setprio(0);
    }
#undef STAGE

    // ========== epilogue: two 128-row half-passes (R12-verified pattern), ===
    // each using the R10/R14-verified [128][136] C tile; wave half = wr
    const int rowg = tid >> 4, lseg = tid & 15;
    if (nb0 < QKW) {
        const float qsc = (nb0 < DIM) ? 0.125f : 1.0f;   // fold 1/sqrt(64) into Q
#pragma unroll
        for (int h = 0; h < 2; ++h) {
            __syncthreads();
            if (wr == h) {
#pragma unroll
                for (int mi = 0; mi < 8; ++mi) {
#pragma unroll
                    for (int nj = 0; nj < 4; ++nj) {
                        const int col = wc * 64 + nj * 16 + fm;
                        const float bs = bias[nb0 + col];
#pragma unroll
                        for (int r = 0; r < 4; ++r) {
                            const int rl = mi * 16 + fg * 4 + r;   // [0,128)
                            lds[rl * 136 + col] = f2bf((acc[mi][nj][r] + bs) * qsc);
                        }
                    }
                }
            }
            __syncthreads();
#pragma unroll
            for (int pp = 0; pp < 8; ++pp) {
                const int row = pp * 16 + rowg;
                const uint4 v = *(const uint4*)&lds[row * 136 + lseg * 8];
                *(uint4*)(QK + (size_t)(m0 + h * 128 + row) * QKW + nb0 + lseg * 8) = v;
            }
        }
    } else {
        const int b8 = m0 >> 10, t0 = m0 & 1023;
#pragma unroll
        for (int h = 0; h < 2; ++h) {
            __syncthreads();
            if (wr == h) {
#pragma unroll
                for (int mi = 0; mi < 8; ++mi) {
                    const int tl = mi * 16 + fg * 4;               // [0,128)
#pragma unroll
                    for (int nj = 0; nj < 4; ++nj) {
                        const int d = wc * 64 + nj * 16 + fm;
                        const float bs = bias[nb0 + d];
                        uint2 u;
                        u.x = (unsigned)f2bf(acc[mi][nj][0] + bs) | ((unsigned)f2bf(acc[mi][nj][1] + bs) << 16);
                        u.y = (unsigned)f2bf(acc[mi][nj][2] + bs) | ((unsigned)f2bf(acc[mi][nj][3] + bs) << 16);
                        *(uint2*)(&lds[d * 136 + tl]) = u;
                    }
                }
            }
            __syncthreads();
#pragma unroll
            for (int pp = 0; pp < 8; ++pp) {
                const int dl = pp * 16 + rowg;
                const int dg = (nb0 - QKW) + dl;
                const uint4 v = *(const uint4*)&lds[dl * 136 + lseg * 8];
                *(uint4*)(VT + ((size_t)((b8 * HEADS + (dg >> 6)) * HD + (dg & 63))) * SEQ
                          + t0 + h * 128 + lseg * 8) = v;
            }
        }
    }
}

// ==================== proj GEMM — R17: branch-fused, single f32 output =====
__global__ __launch_bounds__(256) void gemm_proj_kernel(
    const unsigned short* __restrict__ A0, const unsigned short* __restrict__ BT0,
    const unsigned short* __restrict__ A1, const unsigned short* __restrict__ BT1,
    const float* __restrict__ b0, const float* __restrict__ b1,
    const float* __restrict__ xres, float* __restrict__ Y)
{
    __shared__ __align__(16) unsigned short Als[2][2][64 * 32];    // [br][buf] 16 KB
    __shared__ __align__(16) unsigned short Bls[2][2][128 * 32];   // [br][buf] 32 KB
    const int tid = threadIdx.x, lane = tid & 63, wv = tid >> 6;
    const int m0 = blockIdx.y * 64, n0 = blockIdx.x * 128;
    const int fm = lane & 15, fg = lane >> 4, fk = (lane >> 4) * 8;
    const int srw = lane >> 2, kk = (lane & 3) * 8;
    const int K = DIM;

    const unsigned short* Ag0  = A0  + (size_t)(m0 + wv * 16 + srw) * K + kk;
    const unsigned short* Ag1  = A1  + (size_t)(m0 + wv * 16 + srw) * K + kk;
    const unsigned short* Bg00 = BT0 + (size_t)(n0 + wv * 32 + srw) * K + kk;
    const unsigned short* Bg01 = BT0 + (size_t)(n0 + wv * 32 + 16 + srw) * K + kk;
    const unsigned short* Bg10 = BT1 + (size_t)(n0 + wv * 32 + srw) * K + kk;
    const unsigned short* Bg11 = BT1 + (size_t)(n0 + wv * 32 + 16 + srw) * K + kk;

    f32x4 acc0[4][2], acc1[4][2];
#pragma unroll
    for (int i = 0; i < 4; ++i)
#pragma unroll
        for (int j = 0; j < 2; ++j) {
            acc0[i][j] = f32x4{0.f, 0.f, 0.f, 0.f};
            acc1[i][j] = f32x4{0.f, 0.f, 0.f, 0.f};
        }

    gld_lds16(Ag0,  &Als[0][0][wv * 512]);
    gld_lds16(Bg00, &Bls[0][0][wv * 1024]);
    gld_lds16(Bg01, &Bls[0][0][wv * 1024 + 512]);
    gld_lds16(Ag1,  &Als[1][0][wv * 512]);
    gld_lds16(Bg10, &Bls[1][0][wv * 1024]);
    gld_lds16(Bg11, &Bls[1][0][wv * 1024 + 512]);

    const int NK = K / 32;   // 24
    for (int kt = 0; kt < NK; ++kt) {
        const int p = kt & 1;
        __syncthreads();
        if (kt + 1 < NK) {
            const int off = (kt + 1) * 32;
            gld_lds16(Ag0 + off,  &Als[0][p ^ 1][wv * 512]);
            gld_lds16(Bg00 + off, &Bls[0][p ^ 1][wv * 1024]);
            gld_lds16(Bg01 + off, &Bls[0][p ^ 1][wv * 1024 + 512]);
            gld_lds16(Ag1 + off,  &Als[1][p ^ 1][wv * 512]);
            gld_lds16(Bg10 + off, &Bls[1][p ^ 1][wv * 1024]);
            gld_lds16(Bg11 + off, &Bls[1][p ^ 1][wv * 1024 + 512]);
        }
        short8 af[4], bf[2];
        // ---- branch 0 (causal)
#pragma unroll
        for (int i = 0; i < 4; ++i)
            af[i] = *(const short8*)&Als[0][p][(i * 16 + fm) * 32 + fk];
#pragma unroll
        for (int j = 0; j < 2; ++j)
            bf[j] = *(const short8*)&Bls[0][p][(wv * 32 + j * 16 + fm) * 32 + fk];
#pragma unroll
        for (int i = 0; i < 4; ++i)
#pragma unroll
            for (int j = 0; j < 2; ++j)
                acc0[i][j] = __builtin_amdgcn_mfma_f32_16x16x32_bf16(af[i], bf[j], acc0[i][j], 0, 0, 0);
        // ---- branch 1 (anti-causal)
#pragma unroll
        for (int i = 0; i < 4; ++i)
            af[i] = *(const short8*)&Als[1][p][(i * 16 + fm) * 32 + fk];
#pragma unroll
        for (int j = 0; j < 2; ++j)
            bf[j] = *(const short8*)&Bls[1][p][(wv * 32 + j * 16 + fm) * 32 + fk];
#pragma unroll
        for (int i = 0; i < 4; ++i)
#pragma unroll
            for (int j = 0; j < 2; ++j)
                acc1[i][j] = __builtin_amdgcn_mfma_f32_16x16x32_bf16(af[i], bf[j], acc1[i][j], 0, 0, 0);
    }
    // epilogue: Y = acc_c + acc_ac + x + (b0 + b1), fp32
#pragma unroll
    for (int i = 0; i < 4; ++i) {
        const int m = m0 + i * 16 + fg * 4;
#pragma unroll
        for (int j = 0; j < 2; ++j) {
            const int n = n0 + wv * 32 + j * 16 + fm;
            const float bs = b0[n] + b1[n];
#pragma unroll
            for (int r = 0; r < 4; ++r) {
                const size_t idx = (size_t)(m + r) * DIM + n;
                Y[idx] = acc0[i][j][r] + acc1[i][j][r] + xres[idx] + bs;
            }
        }
    }
}

// ==================== fused MFMA flash attention, dbuf LDS K/V (R17) =======
#define KP 72    // LDS pitch in shorts (144B rows)
__global__ __launch_bounds__(256, 3) void attn_fused_kernel(
    const unsigned short* __restrict__ qk_c, const unsigned short* __restrict__ vT_c,
    const unsigned short* __restrict__ qk_ac, const unsigned short* __restrict__ vT_ac,
    unsigned short* __restrict__ o_c, unsigned short* __restrict__ o_ac)
{
    __shared__ __align__(16) unsigned short Kls[2][64 * KP];   // 18 KB
    __shared__ __align__(16) unsigned short Vls[2][64 * KP];   // 18 KB ([d][kc])
    __shared__ __align__(16) unsigned short Ps[4][16 * KP];    // 9 KB, wave-private
    const int tid = threadIdx.x, lane = tid & 63, w = tid >> 6;
    const int fm = lane & 15, fg = lane >> 4;
    const int bh = blockIdx.x, qt = blockIdx.y;
    const int b = bh / HEADS, h = bh % HEADS;
    unsigned short* Psw = &Ps[w][0];
    const int srow = tid >> 3, sseg = (tid & 7) * 8;

    for (int br = 0; br < 2; ++br) {
        const int causal = (br == 0);
        const unsigned short* __restrict__ qk = causal ? qk_c : qk_ac;
        const unsigned short* __restrict__ vT = causal ? vT_c : vT_ac;
        unsigned short* __restrict__ o = causal ? o_c : o_ac;
        const unsigned short* qbase = qk + (size_t)b * SEQ * QKW + h * HD;
        const unsigned short* kbase = qbase + DIM;
        const unsigned short* vtb   = vT + (size_t)(b * HEADS + h) * HD * SEQ;

        short8 qb0, qb1;
        {
            const size_t qoff = (size_t)(qt * 64 + w * 16 + fm) * QKW + fg * 8;
            qb0 = *(const short8*)(qbase + qoff);
            qb1 = *(const short8*)(qbase + qoff + 32);
        }

        float ls = 0.f;
        f32x4 accO[4];
#pragma unroll
        for (int dj = 0; dj < 4; ++dj) accO[dj] = f32x4{0.f, 0.f, 0.f, 0.f};

        const int ktb = causal ? 0 : qt;
        const int kte = causal ? qt : (SEQ / 64 - 1);

        uint4 kr0 = *(const uint4*)(kbase + (size_t)(ktb * 64 + srow) * QKW + sseg);
        uint4 kr1 = *(const uint4*)(kbase + (size_t)(ktb * 64 + srow + 32) * QKW + sseg);
        uint4 vr0 = *(const uint4*)(vtb + (size_t)srow * SEQ + ktb * 64 + sseg);
        uint4 vr1 = *(const uint4*)(vtb + (size_t)(srow + 32) * SEQ + ktb * 64 + sseg);

        if (br) __syncthreads();
        int p = 0;
        for (int kt = ktb; kt <= kte; ++kt) {
            *(uint4*)(&Kls[p][srow * KP + sseg])        = kr0;
            *(uint4*)(&Kls[p][(srow + 32) * KP + sseg]) = kr1;
            *(uint4*)(&Vls[p][srow * KP + sseg])        = vr0;
            *(uint4*)(&Vls[p][(srow + 32) * KP + sseg]) = vr1;
            if (kt < kte) {
                const int ktn = kt + 1;
                kr0 = *(const uint4*)(kbase + (size_t)(ktn * 64 + srow) * QKW + sseg);
                kr1 = *(const uint4*)(kbase + (size_t)(ktn * 64 + srow + 32) * QKW + sseg);
                vr0 = *(const uint4*)(vtb + (size_t)srow * SEQ + ktn * 64 + sseg);
                vr1 = *(const uint4*)(vtb + (size_t)(srow + 32) * SEQ + ktn * 64 + sseg);
            }
            __syncthreads();

            f32x4 st[4];
#pragma unroll
            for (int kj = 0; kj < 4; ++kj) {
                const short8 ka0 = *(const short8*)&Kls[p][(kj * 16 + fm) * KP + fg * 8];
                const short8 ka1 = *(const short8*)&Kls[p][(kj * 16 + fm) * KP + 32 + fg * 8];
                st[kj] = __builtin_amdgcn_mfma_f32_16x16x32_bf16(ka0, qb0, f32x4{0.f,0.f,0.f,0.f}, 0, 0, 0);
                st[kj] = __builtin_amdgcn_mfma_f32_16x16x32_bf16(ka1, qb1, st[kj], 0, 0, 0);
            }
            const bool diag = (kt == qt);
#pragma unroll
            for (int kj = 0; kj < 4; ++kj) {
                float e[4];
#pragma unroll
                for (int r = 0; r < 4; ++r) {
                    float v = st[kj][r];
                    if (diag) {
                        const int ki = kj * 16 + fg * 4 + r;
                        const int qi = w * 16 + fm;
                        const bool ok = causal ? (ki <= qi) : (ki >= qi);
                        if (!ok) v = -1e30f;
                    }
                    e[r] = __expf(v);
                    ls += e[r];
                }
                // cheap truncate-pack (P >= 0, <=2^-8 one-sided rel err; denom fp32)
                union { float f; unsigned u; } u0, u1, u2, u3;
                u0.f = e[0]; u1.f = e[1]; u2.f = e[2]; u3.f = e[3];
                uint2 u;
                u.x = (u0.u >> 16) | (u1.u & 0xffff0000u);
                u.y = (u2.u >> 16) | (u3.u & 0xffff0000u);
                *(uint2*)(Psw + fm * KP + kj * 16 + fg * 4) = u;
            }
            const short8 ap0 = *(const short8*)(Psw + fm * KP + fg * 8);
            const short8 ap1 = *(const short8*)(Psw + fm * KP + 32 + fg * 8);
#pragma unroll
            for (int dj = 0; dj < 4; ++dj) {
                const short8 vb0 = *(const short8*)&Vls[p][(dj * 16 + fm) * KP + fg * 8];
                const short8 vb1 = *(const short8*)&Vls[p][(dj * 16 + fm) * KP + 32 + fg * 8];
                accO[dj] = __builtin_amdgcn_mfma_f32_16x16x32_bf16(ap0, vb0, accO[dj], 0, 0, 0);
                accO[dj] = __builtin_amdgcn_mfma_f32_16x16x32_bf16(ap1, vb1, accO[dj], 0, 0, 0);
            }
            p ^= 1;
        }

        float lt = ls;
        lt += __shfl_xor(lt, 16);
        lt += __shfl_xor(lt, 32);
        float li_o[4];
#pragma unroll
        for (int r = 0; r < 4; ++r) li_o[r] = __shfl(lt, fg * 4 + r);
#pragma unroll
        for (int r = 0; r < 4; ++r) {
            const float inv = 1.f / li_o[r];
            const int q = qt * 64 + w * 16 + fg * 4 + r;
            unsigned short* orow = o + ((size_t)b * SEQ + q) * DIM + h * HD;
#pragma unroll
            for (int dj = 0; dj < 4; ++dj)
                orow[dj * 16 + fm] = f2bf(accO[dj][r] * inv);
        }
    }
}

// ==================== LayerNorm over last dim (768), Y fp32 ====================
__global__ __launch_bounds__(256) void ln_kernel(
    const float* __restrict__ Y,
    const float* __restrict__ gamma, const float* __restrict__ beta,
    float* __restrict__ out)
{
    const int row = blockIdx.x;
    const int tid = threadIdx.x;
    const float* yr = Y + (size_t)row * DIM;
    float v0 = yr[tid];
    float v1 = yr[tid + 256];
    float v2 = yr[tid + 512];
    float s = v0 + v1 + v2;
    float q = v0 * v0 + v1 * v1 + v2 * v2;
#pragma unroll
    for (int off = 32; off > 0; off >>= 1) {
        s += __shfl_down(s, off);
        q += __shfl_down(q, off);
    }
    __shared__ float rs_[4], rq_[4];
    const int wv = tid >> 6;
    if ((tid & 63) == 0) { rs_[wv] = s; rq_[wv] = q; }
    __syncthreads();
    const float ts = rs_[0] + rs_[1] + rs_[2] + rs_[3];
    const float tq = rq_[0] + rq_[1] + rq_[2] + rq_[3];
    const float mu = ts * (1.f / DIM);
    const float var = tq * (1.f / DIM) - mu * mu;
    const float rstd = rsqrtf(var + EPS);
    out[(size_t)row * DIM + tid]       = (v0 - mu) * rstd * gamma[tid]       + beta[tid];
    out[(size_t)row * DIM + tid + 256] = (v1 - mu) * rstd * gamma[tid + 256] + beta[tid + 256];
    out[(size_t)row * DIM + tid + 512] = (v2 - mu) * rstd * gamma[tid + 512] + beta[tid + 512];
}

// ==================== launch ====================
extern "C" void kernel_launch(void* const* d_in, const int* in_sizes, int n_in,
                              void* d_out, int out_size, void* d_ws, size_t ws_size,
                              hipStream_t stream)
{
    const float* x       = (const float*)d_in[0];
    const float* Wqkv_c  = (const float*)d_in[1];
    const float* bqkv_c  = (const float*)d_in[2];
    const float* Wp_c    = (const float*)d_in[3];
    const float* bp_c    = (const float*)d_in[4];
    const float* Wqkv_ac = (const float*)d_in[5];
    const float* bqkv_ac = (const float*)d_in[6];
    const float* Wp_ac   = (const float*)d_in[7];
    const float* bp_ac   = (const float*)d_in[8];
    const float* gamma   = (const float*)d_in[9];
    const float* beta    = (const float*)d_in[10];
    float* out = (float*)d_out;

    // ws layout, 59.77 MB total:
    char* p = (char*)d_ws;
    unsigned short* qk_c   = (unsigned short*)p; p += (size_t)NTOK * QKW * 2;   // 12.58 MB
    unsigned short* qk_ac  = (unsigned short*)p; p += (size_t)NTOK * QKW * 2;   // 12.58 MB
    unsigned short* vT_c   = (unsigned short*)p; p += (size_t)NTOK * DIM * 2;   // 6.29 MB
    unsigned short* vT_ac  = (unsigned short*)p; p += (size_t)NTOK * DIM * 2;   // 6.29 MB
    unsigned short* o_ac   = (unsigned short*)p; p += (size_t)NTOK * DIM * 2;   // 6.29 MB
    unsigned short* xb     = (unsigned short*)p; p += (size_t)NTOK * DIM * 2;   // 6.29 MB
    unsigned short* WqT_c  = (unsigned short*)p; p += (size_t)QKVW * DIM * 2;   // 3.54 MB
    unsigned short* WqT_ac = (unsigned short*)p; p += (size_t)QKVW * DIM * 2;   // 3.54 MB
    unsigned short* WpT_c  = (unsigned short*)p; p += (size_t)DIM * DIM * 2;    // 1.18 MB
    unsigned short* WpT_ac = (unsigned short*)p; p += (size_t)DIM * DIM * 2;    // 1.18 MB
    // overlays (stream-ordered lifetime, safe):
    unsigned short* o_c = WqT_c;           // attn writes o_c after qkv GEMM's last WqT read
    float*          Y   = (float*)qk_c;    // proj writes Y after attn's last qk read

    cvt_all_kernel<<<CVT_X_BLOCKS + 2 * CVT_WQ_TILES + 2 * CVT_WP_TILES, 256, 0, stream>>>(
        x, Wqkv_c, Wqkv_ac, Wp_c, Wp_ac, xb, WqT_c, WqT_ac, WpT_c, WpT_ac);

    // both QKV GEMMs, 256x128 x BK32, 576 blocks (2D XCD supertile), 2 blk/CU
    gemm_qkv_kernel<<<576, 256, 0, stream>>>(
        xb, WqT_c, WqT_ac, bqkv_c, bqkv_ac, qk_c, qk_ac, vT_c, vT_ac);

    attn_fused_kernel<<<dim3(BATCH * HEADS, SEQ / 64), 256, 0, stream>>>(
        qk_c, vT_c, qk_ac, vT_ac, o_c, o_ac);

    // branch-fused proj: 384 blocks, Y = acc_c + acc_ac + x + b0 + b1 (fp32)
    gemm_proj_kernel<<<dim3(DIM / 128, NTOK / 64), 256, 0, stream>>>(
        o_c, WpT_c, o_ac, WpT_ac, bp_c, bp_ac, x, Y);
    ln_kernel<<<NTOK, 256, 0, stream>>>(Y, gamma, beta, out);
}

// Round 11
// 188.478 us; speedup vs baseline: 1.0628x; 1.0628x over previous
//
#include <hip/hip_runtime.h>
#include <stdint.h>

#define DIM 768
#define HEADS 12
#define HD 64
#define BATCH 4
#define SEQ 1024
#define NTOK (BATCH*SEQ)   // 4096
#define QKVW (3*DIM)       // 2304
#define QKW (2*DIM)        // 1536
#define EPS 1e-5f

typedef __attribute__((ext_vector_type(8))) short short8;   // 8 bf16 (4 VGPRs)
typedef __attribute__((ext_vector_type(4))) float f32x4;    // MFMA C/D

// ---- fp32 <-> bf16 ----
__device__ __forceinline__ unsigned short f2bf(float f) {
    union { float f; unsigned u; } v; v.f = f;
    unsigned r = v.u + 0x7fffu + ((v.u >> 16) & 1u);   // RNE
    return (unsigned short)(r >> 16);
}
__device__ __forceinline__ float b2f(unsigned short s) {
    union { unsigned u; float f; } v; v.u = (unsigned)s << 16; return v.f;
}

// ---- async global->LDS, 16B per lane ----
__device__ __forceinline__ void gld_lds16(const void* g, void* l) {
    auto gp = reinterpret_cast<const __attribute__((address_space(1))) unsigned int*>(
        (uintptr_t)g);
    auto lp = reinterpret_cast<__attribute__((address_space(3))) unsigned int*>(
        (unsigned int)(uintptr_t)l);
    __builtin_amdgcn_global_load_lds(gp, lp, 16, 0, 0);
}

// ==================== combined conversions (1 launch) ====================
#define CVT_X_BLOCKS (NTOK*DIM/4096)            // 768 (4 float4 per thread)
#define CVT_WQ_TILES ((QKVW/32)*(DIM/32))       // 1728
#define CVT_WP_TILES ((DIM/32)*(DIM/32))        // 576
__global__ __launch_bounds__(256) void cvt_all_kernel(
    const float* __restrict__ x,
    const float* __restrict__ Wq0, const float* __restrict__ Wq1,
    const float* __restrict__ Wp0, const float* __restrict__ Wp1,
    unsigned short* __restrict__ xb,
    unsigned short* __restrict__ WqT0, unsigned short* __restrict__ WqT1,
    unsigned short* __restrict__ WpT0, unsigned short* __restrict__ WpT1)
{
    const int bid = blockIdx.x, tid = threadIdx.x;
    if (bid < CVT_X_BLOCKS) {
        const int base = bid * 1024 + tid;
#pragma unroll
        for (int u = 0; u < 4; ++u) {
            const float4 v = ((const float4*)x)[base + u * 256];
            ushort4 o4;
            o4.x = f2bf(v.x); o4.y = f2bf(v.y); o4.z = f2bf(v.z); o4.w = f2bf(v.w);
            ((ushort4*)xb)[base + u * 256] = o4;
        }
        return;
    }
    __shared__ float t[32][33];
    const float* W; unsigned short* WT; int N, K, tile;
    int w = bid - CVT_X_BLOCKS;
    if (w < 2 * CVT_WQ_TILES) {
        const int z = w / CVT_WQ_TILES; tile = w % CVT_WQ_TILES;
        W = z ? Wq1 : Wq0; WT = z ? WqT1 : WqT0; N = QKVW; K = DIM;
    } else {
        w -= 2 * CVT_WQ_TILES;
        const int z = w / CVT_WP_TILES; tile = w % CVT_WP_TILES;
        W = z ? Wp1 : Wp0; WT = z ? WpT1 : WpT0; N = DIM; K = DIM;
    }
    const int ntiles = N / 32;
    const int n0 = (tile % ntiles) * 32, k0 = (tile / ntiles) * 32;
    const int c = tid & 31, rr = tid >> 5;
#pragma unroll
    for (int i = 0; i < 4; ++i)
        t[rr + 8 * i][c] = W[(size_t)(k0 + rr + 8 * i) * N + n0 + c];
    __syncthreads();
#pragma unroll
    for (int i = 0; i < 4; ++i)
        WT[(size_t)(n0 + rr + 8 * i) * K + k0 + c] = f2bf(t[c][rr + 8 * i]);
}

// ==================== fused QKV GEMM — R17: R14 body + R16 2D XCD supertile
// Best measured config (42.0us, MfmaUtil 25.4%, FETCH 42.5MB). R20's 256x128
// BK32 regressed (52us: 2x sync points beat -27% staging traffic) -> BK=64
// with 12 sync points is the family optimum at K=768. Family exhausted per
// decision rule; holding this configuration.
__global__ __launch_bounds__(256, 2) void gemm_qkv_kernel(
    const unsigned short* __restrict__ A,     // xb [4096][768]
    const unsigned short* __restrict__ BT0, const unsigned short* __restrict__ BT1,
    const float* __restrict__ bias0, const float* __restrict__ bias1,
    unsigned short* __restrict__ QK0, unsigned short* __restrict__ QK1,
    unsigned short* __restrict__ VT0, unsigned short* __restrict__ VT1)
{
    const int gid = blockIdx.x;
    // 2D XCD supertile: XCD g=(r,c) in 2x4 owns by[16r,16r+16) x bxz[9c,9c+9)
    const int g = gid & 7, l = gid >> 3;           // l in [0,144)
    const int by  = (g >> 2) * 16 + (l & 15);      // 0..31
    const int bxz = (g & 3) * 9 + (l >> 4);        // 0..35
    const int z = (bxz >= 18) ? 1 : 0;
    const int bx = z ? bxz - 18 : bxz;             // branch-local N tile 0..17
    const unsigned short* __restrict__ BT = z ? BT1 : BT0;
    const float* __restrict__ bias = z ? bias1 : bias0;
    unsigned short* __restrict__ QK = z ? QK1 : QK0;
    unsigned short* __restrict__ VT = z ? VT1 : VT0;
    const int m0 = by * 128;
    const int nb0 = bx * 128;

    // LDS 32768 shorts = 64 KiB: A dbuf 2x8192, B dbuf 2x8192 (@16384).
    // Epilogue reuses [0,17408) as C tile [128][136].
    __shared__ __align__(16) unsigned short lds[32768];

    const int tid = threadIdx.x, lane = tid & 63, wv = tid >> 6;
    const int fm = lane & 15, fg = lane >> 4;
    const int wr = wv >> 1, wc = wv & 1;            // wave grid 2(M) x 2(N)

    // staging: call j covers rows j*32 + wv*8 + (lane>>3); lane chunk' = lane&7
    // holds global chunk (lane&7)^(row&7), row&7 = lane>>3 (T2 pre-swizzled src)
    const int sr8 = lane >> 3;                      // 0..7
    const int sc = ((lane & 7) ^ sr8) * 8;
    const unsigned short* pA = A  + (size_t)(m0  + wv * 8 + sr8) * DIM + sc;
    const unsigned short* pB = BT + (size_t)(nb0 + wv * 8 + sr8) * DIM + sc;
    unsigned short* dA = lds + wv * 512;            // wave-uniform dest bases
    unsigned short* dB = lds + 16384 + wv * 512;

    // ds_read: frag (row, ks, fg) at chunk ((ks<<2)|fg) ^ (row&7); row&7 = fm&7
    const int swz = fm & 7;
    const int cK0 = ((0 + fg) ^ swz) * 8;
    const int cK1 = ((4 + fg) ^ swz) * 8;
    const int aB = (wr * 64 + fm) * 64;
    const int bB = (wc * 64 + fm) * 64;

    f32x4 acc[4][4];
#pragma unroll
    for (int i = 0; i < 4; ++i)
#pragma unroll
        for (int j = 0; j < 4; ++j) acc[i][j] = f32x4{0.f, 0.f, 0.f, 0.f};

    short8 a[4][2], b[4][2];

    // prologue: stage tile 0 into buffer 0 (A 4 calls + B 4 calls)
#pragma unroll
    for (int j = 0; j < 4; ++j) {
        gld_lds16(pA + j * 32 * DIM, dA + j * 2048);
        gld_lds16(pB + j * 32 * DIM, dB + j * 2048);
    }

    for (int t = 0; t < 12; ++t) {
        const int ab = (t & 1) * 8192;              // A buffer (read)
        const int bb = 16384 + (t & 1) * 8192;      // B buffer (read)
        const int nb2 = ((t + 1) & 1) * 8192;       // staging buffer (write)

        // own tile-t loads landed; barrier publishes all waves' loads and
        // confirms all readers of buf^1 (tile t-1) are done
        asm volatile("s_waitcnt vmcnt(0)" ::: "memory");
        __builtin_amdgcn_s_barrier();
        if (t < 11) {
            const int kN = (t + 1) * 64;
#pragma unroll
            for (int j = 0; j < 4; ++j) {
                gld_lds16(pA + kN + j * 32 * DIM, dA + nb2 + j * 2048);
                gld_lds16(pB + kN + j * 32 * DIM, dB + nb2 + j * 2048);
            }
        }

        // ---- cluster 1: A (8 reads) + B nj=0,1 (4 reads); mfma mi x nj01
#pragma unroll
        for (int mi = 0; mi < 4; ++mi) {
            a[mi][0] = *(const short8*)&lds[ab + aB + mi * 1024 + cK0];
            a[mi][1] = *(const short8*)&lds[ab + aB + mi * 1024 + cK1];
        }
#pragma unroll
        for (int nj = 0; nj < 2; ++nj) {
            b[nj][0] = *(const short8*)&lds[bb + bB + nj * 1024 + cK0];
            b[nj][1] = *(const short8*)&lds[bb + bB + nj * 1024 + cK1];
        }
        asm volatile("s_waitcnt lgkmcnt(0)" ::: "memory");
        __builtin_amdgcn_sched_barrier(0);
        __builtin_amdgcn_s_setprio(1);
#pragma unroll
        for (int ks = 0; ks < 2; ++ks)
#pragma unroll
            for (int mi = 0; mi < 4; ++mi)
#pragma unroll
                for (int nj = 0; nj < 2; ++nj)
                    acc[mi][nj] = __builtin_amdgcn_mfma_f32_16x16x32_bf16(
                        a[mi][ks], b[nj][ks], acc[mi][nj], 0, 0, 0);
        __builtin_amdgcn_s_setprio(0);

        // ---- cluster 2: B nj=2,3 (4 reads); mfma mi x nj23
#pragma unroll
        for (int nj = 2; nj < 4; ++nj) {
            b[nj][0] = *(const short8*)&lds[bb + bB + nj * 1024 + cK0];
            b[nj][1] = *(const short8*)&lds[bb + bB + nj * 1024 + cK1];
        }
        asm volatile("s_waitcnt lgkmcnt(0)" ::: "memory");
        __builtin_amdgcn_sched_barrier(0);
        __builtin_amdgcn_s_setprio(1);
#pragma unroll
        for (int ks = 0; ks < 2; ++ks)
#pragma unroll
            for (int mi = 0; mi < 4; ++mi)
#pragma unroll
                for (int nj = 2; nj < 4; ++nj)
                    acc[mi][nj] = __builtin_amdgcn_mfma_f32_16x16x32_bf16(
                        a[mi][ks], b[nj][ks], acc[mi][nj], 0, 0, 0);
        __builtin_amdgcn_s_setprio(0);
    }

    // ========== epilogue (R10-verified layout): C tile [128][136] ==========
    __syncthreads();
    const int rowg = tid >> 4, lseg = tid & 15;
    if (nb0 < QKW) {
        const float qsc = (nb0 < DIM) ? 0.125f : 1.0f;   // fold 1/sqrt(64) into Q
#pragma unroll
        for (int i = 0; i < 4; ++i) {
            const int ml = wr * 64 + i * 16 + fg * 4;
#pragma unroll
            for (int j = 0; j < 4; ++j) {
                const int nl = wc * 64 + j * 16 + fm;
                const float bs = bias[nb0 + nl];
#pragma unroll
                for (int r = 0; r < 4; ++r)
                    lds[(ml + r) * 136 + nl] = f2bf((acc[i][j][r] + bs) * qsc);
            }
        }
        __syncthreads();
#pragma unroll
        for (int pp = 0; pp < 8; ++pp) {
            const int row = pp * 16 + rowg;
            const uint4 v = *(const uint4*)&lds[row * 136 + lseg * 8];
            *(uint4*)(QK + (size_t)(m0 + row) * QKW + nb0 + lseg * 8) = v;
        }
    } else {
        const int b8 = m0 >> 10, t0 = m0 & 1023;
#pragma unroll
        for (int i = 0; i < 4; ++i) {
            const int tl = wr * 64 + i * 16 + fg * 4;
#pragma unroll
            for (int j = 0; j < 4; ++j) {
                const int nl = wc * 64 + j * 16 + fm;
                const float bs = bias[nb0 + nl];
                uint2 u;
                u.x = (unsigned)f2bf(acc[i][j][0] + bs) | ((unsigned)f2bf(acc[i][j][1] + bs) << 16);
                u.y = (unsigned)f2bf(acc[i][j][2] + bs) | ((unsigned)f2bf(acc[i][j][3] + bs) << 16);
                *(uint2*)(&lds[nl * 136 + tl]) = u;
            }
        }
        __syncthreads();
#pragma unroll
        for (int pp = 0; pp < 8; ++pp) {
            const int nl = pp * 16 + rowg;
            const int nh = (nb0 - QKW) + nl;
            const uint4 v = *(const uint4*)&lds[nl * 136 + lseg * 8];
            *(uint4*)(VT + ((size_t)((b8 * HEADS + (nh >> 6)) * HD + (nh & 63))) * SEQ
                      + t0 + lseg * 8) = v;
        }
    }
}

// ==================== proj GEMM — R17: branch-fused, single f32 output =====
__global__ __launch_bounds__(256) void gemm_proj_kernel(
    const unsigned short* __restrict__ A0, const unsigned short* __restrict__ BT0,
    const unsigned short* __restrict__ A1, const unsigned short* __restrict__ BT1,
    const float* __restrict__ b0, const float* __restrict__ b1,
    const float* __restrict__ xres, float* __restrict__ Y)
{
    __shared__ __align__(16) unsigned short Als[2][2][64 * 32];    // [br][buf] 16 KB
    __shared__ __align__(16) unsigned short Bls[2][2][128 * 32];   // [br][buf] 32 KB
    const int tid = threadIdx.x, lane = tid & 63, wv = tid >> 6;
    const int m0 = blockIdx.y * 64, n0 = blockIdx.x * 128;
    const int fm = lane & 15, fg = lane >> 4, fk = (lane >> 4) * 8;
    const int srw = lane >> 2, kk = (lane & 3) * 8;
    const int K = DIM;

    const unsigned short* Ag0  = A0  + (size_t)(m0 + wv * 16 + srw) * K + kk;
    const unsigned short* Ag1  = A1  + (size_t)(m0 + wv * 16 + srw) * K + kk;
    const unsigned short* Bg00 = BT0 + (size_t)(n0 + wv * 32 + srw) * K + kk;
    const unsigned short* Bg01 = BT0 + (size_t)(n0 + wv * 32 + 16 + srw) * K + kk;
    const unsigned short* Bg10 = BT1 + (size_t)(n0 + wv * 32 + srw) * K + kk;
    const unsigned short* Bg11 = BT1 + (size_t)(n0 + wv * 32 + 16 + srw) * K + kk;

    f32x4 acc0[4][2], acc1[4][2];
#pragma unroll
    for (int i = 0; i < 4; ++i)
#pragma unroll
        for (int j = 0; j < 2; ++j) {
            acc0[i][j] = f32x4{0.f, 0.f, 0.f, 0.f};
            acc1[i][j] = f32x4{0.f, 0.f, 0.f, 0.f};
        }

    gld_lds16(Ag0,  &Als[0][0][wv * 512]);
    gld_lds16(Bg00, &Bls[0][0][wv * 1024]);
    gld_lds16(Bg01, &Bls[0][0][wv * 1024 + 512]);
    gld_lds16(Ag1,  &Als[1][0][wv * 512]);
    gld_lds16(Bg10, &Bls[1][0][wv * 1024]);
    gld_lds16(Bg11, &Bls[1][0][wv * 1024 + 512]);

    const int NK = K / 32;   // 24
    for (int kt = 0; kt < NK; ++kt) {
        const int p = kt & 1;
        __syncthreads();
        if (kt + 1 < NK) {
            const int off = (kt + 1) * 32;
            gld_lds16(Ag0 + off,  &Als[0][p ^ 1][wv * 512]);
            gld_lds16(Bg00 + off, &Bls[0][p ^ 1][wv * 1024]);
            gld_lds16(Bg01 + off, &Bls[0][p ^ 1][wv * 1024 + 512]);
            gld_lds16(Ag1 + off,  &Als[1][p ^ 1][wv * 512]);
            gld_lds16(Bg10 + off, &Bls[1][p ^ 1][wv * 1024]);
            gld_lds16(Bg11 + off, &Bls[1][p ^ 1][wv * 1024 + 512]);
        }
        short8 af[4], bf[2];
        // ---- branch 0 (causal)
#pragma unroll
        for (int i = 0; i < 4; ++i)
            af[i] = *(const short8*)&Als[0][p][(i * 16 + fm) * 32 + fk];
#pragma unroll
        for (int j = 0; j < 2; ++j)
            bf[j] = *(const short8*)&Bls[0][p][(wv * 32 + j * 16 + fm) * 32 + fk];
#pragma unroll
        for (int i = 0; i < 4; ++i)
#pragma unroll
            for (int j = 0; j < 2; ++j)
                acc0[i][j] = __builtin_amdgcn_mfma_f32_16x16x32_bf16(af[i], bf[j], acc0[i][j], 0, 0, 0);
        // ---- branch 1 (anti-causal)
#pragma unroll
        for (int i = 0; i < 4; ++i)
            af[i] = *(const short8*)&Als[1][p][(i * 16 + fm) * 32 + fk];
#pragma unroll
        for (int j = 0; j < 2; ++j)
            bf[j] = *(const short8*)&Bls[1][p][(wv * 32 + j * 16 + fm) * 32 + fk];
#pragma unroll
        for (int i = 0; i < 4; ++i)
#pragma unroll
            for (int j = 0; j < 2; ++j)
                acc1[i][j] = __builtin_amdgcn_mfma_f32_16x16x32_bf16(af[i], bf[j], acc1[i][j], 0, 0, 0);
    }
    // epilogue: Y = acc_c + acc_ac + x + (b0 + b1), fp32
#pragma unroll
    for (int i = 0; i < 4; ++i) {
        const int m = m0 + i * 16 + fg * 4;
#pragma unroll
        for (int j = 0; j < 2; ++j) {
            const int n = n0 + wv * 32 + j * 16 + fm;
            const float bs = b0[n] + b1[n];
#pragma unroll
            for (int r = 0; r < 4; ++r) {
                const size_t idx = (size_t)(m + r) * DIM + n;
                Y[idx] = acc0[i][j][r] + acc1[i][j][r] + xres[idx] + bs;
            }
        }
    }
}

// ==================== fused MFMA flash attention, dbuf LDS K/V (R17) =======
#define KP 72    // LDS pitch in shorts (144B rows)
__global__ __launch_bounds__(256, 3) void attn_fused_kernel(
    const unsigned short* __restrict__ qk_c, const unsigned short* __restrict__ vT_c,
    const unsigned short* __restrict__ qk_ac, const unsigned short* __restrict__ vT_ac,
    unsigned short* __restrict__ o_c, unsigned short* __restrict__ o_ac)
{
    __shared__ __align__(16) unsigned short Kls[2][64 * KP];   // 18 KB
    __shared__ __align__(16) unsigned short Vls[2][64 * KP];   // 18 KB ([d][kc])
    __shared__ __align__(16) unsigned short Ps[4][16 * KP];    // 9 KB, wave-private
    const int tid = threadIdx.x, lane = tid & 63, w = tid >> 6;
    const int fm = lane & 15, fg = lane >> 4;
    const int bh = blockIdx.x, qt = blockIdx.y;
    const int b = bh / HEADS, h = bh % HEADS;
    unsigned short* Psw = &Ps[w][0];
    const int srow = tid >> 3, sseg = (tid & 7) * 8;

    for (int br = 0; br < 2; ++br) {
        const int causal = (br == 0);
        const unsigned short* __restrict__ qk = causal ? qk_c : qk_ac;
        const unsigned short* __restrict__ vT = causal ? vT_c : vT_ac;
        unsigned short* __restrict__ o = causal ? o_c : o_ac;
        const unsigned short* qbase = qk + (size_t)b * SEQ * QKW + h * HD;
        const unsigned short* kbase = qbase + DIM;
        const unsigned short* vtb   = vT + (size_t)(b * HEADS + h) * HD * SEQ;

        short8 qb0, qb1;
        {
            const size_t qoff = (size_t)(qt * 64 + w * 16 + fm) * QKW + fg * 8;
            qb0 = *(const short8*)(qbase + qoff);
            qb1 = *(const short8*)(qbase + qoff + 32);
        }

        float ls = 0.f;
        f32x4 accO[4];
#pragma unroll
        for (int dj = 0; dj < 4; ++dj) accO[dj] = f32x4{0.f, 0.f, 0.f, 0.f};

        const int ktb = causal ? 0 : qt;
        const int kte = causal ? qt : (SEQ / 64 - 1);

        uint4 kr0 = *(const uint4*)(kbase + (size_t)(ktb * 64 + srow) * QKW + sseg);
        uint4 kr1 = *(const uint4*)(kbase + (size_t)(ktb * 64 + srow + 32) * QKW + sseg);
        uint4 vr0 = *(const uint4*)(vtb + (size_t)srow * SEQ + ktb * 64 + sseg);
        uint4 vr1 = *(const uint4*)(vtb + (size_t)(srow + 32) * SEQ + ktb * 64 + sseg);

        if (br) __syncthreads();
        int p = 0;
        for (int kt = ktb; kt <= kte; ++kt) {
            *(uint4*)(&Kls[p][srow * KP + sseg])        = kr0;
            *(uint4*)(&Kls[p][(srow + 32) * KP + sseg]) = kr1;
            *(uint4*)(&Vls[p][srow * KP + sseg])        = vr0;
            *(uint4*)(&Vls[p][(srow + 32) * KP + sseg]) = vr1;
            if (kt < kte) {
                const int ktn = kt + 1;
                kr0 = *(const uint4*)(kbase + (size_t)(ktn * 64 + srow) * QKW + sseg);
                kr1 = *(const uint4*)(kbase + (size_t)(ktn * 64 + srow + 32) * QKW + sseg);
                vr0 = *(const uint4*)(vtb + (size_t)srow * SEQ + ktn * 64 + sseg);
                vr1 = *(const uint4*)(vtb + (size_t)(srow + 32) * SEQ + ktn * 64 + sseg);
            }
            __syncthreads();

            f32x4 st[4];
#pragma unroll
            for (int kj = 0; kj < 4; ++kj) {
                const short8 ka0 = *(const short8*)&Kls[p][(kj * 16 + fm) * KP + fg * 8];
                const short8 ka1 = *(const short8*)&Kls[p][(kj * 16 + fm) * KP + 32 + fg * 8];
                st[kj] = __builtin_amdgcn_mfma_f32_16x16x32_bf16(ka0, qb0, f32x4{0.f,0.f,0.f,0.f}, 0, 0, 0);
                st[kj] = __builtin_amdgcn_mfma_f32_16x16x32_bf16(ka1, qb1, st[kj], 0, 0, 0);
            }
            const bool diag = (kt == qt);
#pragma unroll
            for (int kj = 0; kj < 4; ++kj) {
                float e[4];
#pragma unroll
                for (int r = 0; r < 4; ++r) {
                    float v = st[kj][r];
                    if (diag) {
                        const int ki = kj * 16 + fg * 4 + r;
                        const int qi = w * 16 + fm;
                        const bool ok = causal ? (ki <= qi) : (ki >= qi);
                        if (!ok) v = -1e30f;
                    }
                    e[r] = __expf(v);
                    ls += e[r];
                }
                // cheap truncate-pack (P >= 0, <=2^-8 one-sided rel err; denom fp32)
                union { float f; unsigned u; } u0, u1, u2, u3;
                u0.f = e[0]; u1.f = e[1]; u2.f = e[2]; u3.f = e[3];
                uint2 u;
                u.x = (u0.u >> 16) | (u1.u & 0xffff0000u);
                u.y = (u2.u >> 16) | (u3.u & 0xffff0000u);
                *(uint2*)(Psw + fm * KP + kj * 16 + fg * 4) = u;
            }
            const short8 ap0 = *(const short8*)(Psw + fm * KP + fg * 8);
            const short8 ap1 = *(const short8*)(Psw + fm * KP + 32 + fg * 8);
#pragma unroll
            for (int dj = 0; dj < 4; ++dj) {
                const short8 vb0 = *(const short8*)&Vls[p][(dj * 16 + fm) * KP + fg * 8];
                const short8 vb1 = *(const short8*)&Vls[p][(dj * 16 + fm) * KP + 32 + fg * 8];
                accO[dj] = __builtin_amdgcn_mfma_f32_16x16x32_bf16(ap0, vb0, accO[dj], 0, 0, 0);
                accO[dj] = __builtin_amdgcn_mfma_f32_16x16x32_bf16(ap1, vb1, accO[dj], 0, 0, 0);
            }
            p ^= 1;
        }

        float lt = ls;
        lt += __shfl_xor(lt, 16);
        lt += __shfl_xor(lt, 32);
        float li_o[4];
#pragma unroll
        for (int r = 0; r < 4; ++r) li_o[r] = __shfl(lt, fg * 4 + r);
#pragma unroll
        for (int r = 0; r < 4; ++r) {
            const float inv = 1.f / li_o[r];
            const int q = qt * 64 + w * 16 + fg * 4 + r;
            unsigned short* orow = o + ((size_t)b * SEQ + q) * DIM + h * HD;
#pragma unroll
            for (int dj = 0; dj < 4; ++dj)
                orow[dj * 16 + fm] = f2bf(accO[dj][r] * inv);
        }
    }
}

// ==================== LayerNorm over last dim (768), Y fp32 ====================
__global__ __launch_bounds__(256) void ln_kernel(
    const float* __restrict__ Y,
    const float* __restrict__ gamma, const float* __restrict__ beta,
    float* __restrict__ out)
{
    const int row = blockIdx.x;
    const int tid = threadIdx.x;
    const float* yr = Y + (size_t)row * DIM;
    float v0 = yr[tid];
    float v1 = yr[tid + 256];
    float v2 = yr[tid + 512];
    float s = v0 + v1 + v2;
    float q = v0 * v0 + v1 * v1 + v2 * v2;
#pragma unroll
    for (int off = 32; off > 0; off >>= 1) {
        s += __shfl_down(s, off);
        q += __shfl_down(q, off);
    }
    __shared__ float rs_[4], rq_[4];
    const int wv = tid >> 6;
    if ((tid & 63) == 0) { rs_[wv] = s; rq_[wv] = q; }
    __syncthreads();
    const float ts = rs_[0] + rs_[1] + rs_[2] + rs_[3];
    const float tq = rq_[0] + rq_[1] + rq_[2] + rq_[3];
    const float mu = ts * (1.f / DIM);
    const float var = tq * (1.f / DIM) - mu * mu;
    const float rstd = rsqrtf(var + EPS);
    out[(size_t)row * DIM + tid]       = (v0 - mu) * rstd * gamma[tid]       + beta[tid];
    out[(size_t)row * DIM + tid + 256] = (v1 - mu) * rstd * gamma[tid + 256] + beta[tid + 256];
    out[(size_t)row * DIM + tid + 512] = (v2 - mu) * rstd * gamma[tid + 512] + beta[tid + 512];
}

// ==================== launch ====================
extern "C" void kernel_launch(void* const* d_in, const int* in_sizes, int n_in,
                              void* d_out, int out_size, void* d_ws, size_t ws_size,
                              hipStream_t stream)
{
    const float* x       = (const float*)d_in[0];
    const float* Wqkv_c  = (const float*)d_in[1];
    const float* bqkv_c  = (const float*)d_in[2];
    const float* Wp_c    = (const float*)d_in[3];
    const float* bp_c    = (const float*)d_in[4];
    const float* Wqkv_ac = (const float*)d_in[5];
    const float* bqkv_ac = (const float*)d_in[6];
    const float* Wp_ac   = (const float*)d_in[7];
    const float* bp_ac   = (const float*)d_in[8];
    const float* gamma   = (const float*)d_in[9];
    const float* beta    = (const float*)d_in[10];
    float* out = (float*)d_out;

    // ws layout, 59.77 MB total:
    char* p = (char*)d_ws;
    unsigned short* qk_c   = (unsigned short*)p; p += (size_t)NTOK * QKW * 2;   // 12.58 MB
    unsigned short* qk_ac  = (unsigned short*)p; p += (size_t)NTOK * QKW * 2;   // 12.58 MB
    unsigned short* vT_c   = (unsigned short*)p; p += (size_t)NTOK * DIM * 2;   // 6.29 MB
    unsigned short* vT_ac  = (unsigned short*)p; p += (size_t)NTOK * DIM * 2;   // 6.29 MB
    unsigned short* o_ac   = (unsigned short*)p; p += (size_t)NTOK * DIM * 2;   // 6.29 MB
    unsigned short* xb     = (unsigned short*)p; p += (size_t)NTOK * DIM * 2;   // 6.29 MB
    unsigned short* WqT_c  = (unsigned short*)p; p += (size_t)QKVW * DIM * 2;   // 3.54 MB
    unsigned short* WqT_ac = (unsigned short*)p; p += (size_t)QKVW * DIM * 2;   // 3.54 MB
    unsigned short* WpT_c  = (unsigned short*)p; p += (size_t)DIM * DIM * 2;    // 1.18 MB
    unsigned short* WpT_ac = (unsigned short*)p; p += (size_t)DIM * DIM * 2;    // 1.18 MB
    // overlays (stream-ordered lifetime, safe):
    unsigned short* o_c = WqT_c;           // attn writes o_c after qkv GEMM's last WqT read
    float*          Y   = (float*)qk_c;    // proj writes Y after attn's last qk read

    cvt_all_kernel<<<CVT_X_BLOCKS + 2 * CVT_WQ_TILES + 2 * CVT_WP_TILES, 256, 0, stream>>>(
        x, Wqkv_c, Wqkv_ac, Wp_c, Wp_ac, xb, WqT_c, WqT_ac, WpT_c, WpT_ac);

    // both QKV GEMMs, 128^2 x BK64, 1152 blocks (2D XCD supertile), 2 blocks/CU
    gemm_qkv_kernel<<<1152, 256, 0, stream>>>(
        xb, WqT_c, WqT_ac, bqkv_c, bqkv_ac, qk_c, qk_ac, vT_c, vT_ac);

    attn_fused_kernel<<<dim3(BATCH * HEADS, SEQ / 64), 256, 0, stream>>>(
        qk_c, vT_c, qk_ac, vT_ac, o_c, o_ac);

    // branch-fused proj: 384 blocks, Y = acc_c + acc_ac + x + b0 + b1 (fp32)
    gemm_proj_kernel<<<dim3(DIM / 128, NTOK / 64), 256, 0, stream>>>(
        o_c, WpT_c, o_ac, WpT_ac, bp_c, bp_ac, x, Y);
    ln_kernel<<<NTOK, 256, 0, stream>>>(Y, gamma, beta, out);
}